// Round 1
// baseline (110.520 us; speedup 1.0000x reference)
//
#include <hip/hip_runtime.h>

#define H_DIM 2048
#define W_DIM 4096
#define C_DIM 3
#define N_ELEM (H_DIM * W_DIM * C_DIM)
#define N_PIX  (H_DIM * W_DIM)

// ---------------- Pass 1: global max of inputs (all values >= 0) ----------------
__global__ __launch_bounds__(256) void max_reduce_kernel(const float* __restrict__ in,
                                                         unsigned int* __restrict__ ws,
                                                         int n4) {
    const float4* in4 = (const float4*)in;
    float m = 0.0f;
    int stride = gridDim.x * blockDim.x;
    for (int i = blockIdx.x * blockDim.x + threadIdx.x; i < n4; i += stride) {
        float4 v = in4[i];
        m = fmaxf(fmaxf(m, v.x), fmaxf(v.y, fmaxf(v.z, v.w)));
    }
    // wave (64-lane) reduce
    #pragma unroll
    for (int off = 32; off > 0; off >>= 1)
        m = fmaxf(m, __shfl_down(m, off, 64));
    __shared__ float smax[4];
    int lane = threadIdx.x & 63;
    int wave = threadIdx.x >> 6;
    if (lane == 0) smax[wave] = m;
    __syncthreads();
    if (threadIdx.x == 0) {
        float bm = fmaxf(fmaxf(smax[0], smax[1]), fmaxf(smax[2], smax[3]));
        atomicMax(ws, __float_as_uint(bm));  // valid ordering for non-negative floats
    }
}

// ---------------- Pass 2: elastic warp with bilinear sampling ----------------
__global__ __launch_bounds__(256) void elastic_sample_kernel(const float* __restrict__ in,
                                                             const float* __restrict__ disp,
                                                             const unsigned int* __restrict__ wsmax,
                                                             float* __restrict__ out) {
    int idx = blockIdx.x * blockDim.x + threadIdx.x;
    if (idx >= N_PIX) return;
    int y = idx >> 12;           // W = 4096 = 2^12
    int x = idx & (W_DIM - 1);

    float cval = __uint_as_float(*wsmax);

    // control-grid (3x3) bilinear weights for this pixel
    const float sy = 2.0f / (float)(H_DIM - 1);
    const float sx = 2.0f / (float)(W_DIM - 1);
    float uy = (float)y * sy;                 // in [0,2]
    float ux = (float)x * sx;
    int iy = min((int)uy, 1);                 // floor (uy >= 0), clipped to n_ctrl-2
    int ix = min((int)ux, 1);
    float fyc = uy - (float)iy;
    float fxc = ux - (float)ix;

    float dense[2];
    #pragma unroll
    for (int d = 0; d < 2; d++) {
        const float* dp = disp + d * 9;
        float a = dp[iy * 3 + ix];
        float b = dp[iy * 3 + ix + 1];
        float c = dp[(iy + 1) * 3 + ix];
        float e = dp[(iy + 1) * 3 + ix + 1];
        float top = (1.0f - fxc) * a + fxc * b;
        float bot = (1.0f - fxc) * c + fxc * e;
        dense[d] = 5.0f * ((1.0f - fyc) * top + fyc * bot);
    }

    float cy = (float)y + dense[0];
    float cx = (float)x + dense[1];
    float y0f = floorf(cy);
    float x0f = floorf(cx);
    float fy = cy - y0f;
    float fx = cx - x0f;
    int y0 = (int)y0f;
    int x0 = (int)x0f;

    float acc0 = 0.0f, acc1 = 0.0f, acc2 = 0.0f;
    #pragma unroll
    for (int j = 0; j < 2; j++) {
        #pragma unroll
        for (int i = 0; i < 2; i++) {
            int yy = y0 + j;
            int xx = x0 + i;
            bool valid = (yy >= 0) & (yy < H_DIM) & (xx >= 0) & (xx < W_DIM);
            int yc = min(max(yy, 0), H_DIM - 1);
            int xc = min(max(xx, 0), W_DIM - 1);
            const float* p = in + ((size_t)yc * W_DIM + xc) * 3;
            float w = (j ? fy : (1.0f - fy)) * (i ? fx : (1.0f - fx));
            float s0 = valid ? p[0] : cval;
            float s1 = valid ? p[1] : cval;
            float s2 = valid ? p[2] : cval;
            acc0 = fmaf(w, s0, acc0);
            acc1 = fmaf(w, s1, acc1);
            acc2 = fmaf(w, s2, acc2);
        }
    }

    float* o = out + (size_t)idx * 3;
    o[0] = acc0;
    o[1] = acc1;
    o[2] = acc2;
}

extern "C" void kernel_launch(void* const* d_in, const int* in_sizes, int n_in,
                              void* d_out, int out_size, void* d_ws, size_t ws_size,
                              hipStream_t stream) {
    const float* in   = (const float*)d_in[0];   // [2048, 4096, 3] f32
    const float* disp = (const float*)d_in[1];   // [2, 3, 3] f32
    float* out = (float*)d_out;
    unsigned int* wsmax = (unsigned int*)d_ws;

    hipMemsetAsync(d_ws, 0, sizeof(unsigned int), stream);

    int n4 = N_ELEM / 4;  // 25165824 / 4, exact
    max_reduce_kernel<<<2048, 256, 0, stream>>>(in, wsmax, n4);

    int blocks = N_PIX / 256;  // exact: 8388608 / 256 = 32768
    elastic_sample_kernel<<<blocks, 256, 0, stream>>>(in, disp, wsmax, out);
}